// Round 1
// baseline (52.750 us; speedup 1.0000x reference)
//
#include <hip/hip_runtime.h>
#include <math.h>

// Problem constants (match reference)
constexpr int Bn = 512;
constexpr int Tn = 512;
constexpr int Dn = 128;
constexpr int Hn = 128;
constexpr int NT = 512;           // threads per block == Tn (one thread per t)
constexpr int NW = NT / 64;       // waves per block

__global__ __launch_bounds__(NT)
void single_attn_kernel(const float* __restrict__ input,   // [B,T,D]
                        const int*   __restrict__ mask,    // [B,T]
                        const float* __restrict__ Wt,      // [D,H]
                        const float* __restrict__ Wx,      // [D,H]
                        const float* __restrict__ rate,    // [1]
                        float* __restrict__ out_v,         // [B,D]
                        float* __restrict__ out_a)         // [B,T]
{
    const int b    = blockIdx.x;
    const int tid  = threadIdx.x;
    const int lane = tid & 63;
    const int wid  = tid >> 6;
    const float* __restrict__ inb = input + (size_t)b * Tn * Dn;

    __shared__ float lv[Dn];
    __shared__ float qs[Hn];
    __shared__ float us[Dn];
    __shared__ float sa[Tn];
    __shared__ float red[NW];
    __shared__ int   ired[NW];
    __shared__ float4 vp[16][32];

    // ---- last_idx = sum(mask[b,:]) - 1 (block reduce) ----
    const int mv = mask[b * Tn + tid];
    {
        int ms = mv;
        #pragma unroll
        for (int off = 32; off > 0; off >>= 1) ms += __shfl_down(ms, off, 64);
        if (lane == 0) ired[wid] = ms;
    }
    __syncthreads();
    int last_idx;
    {
        int s = 0;
        #pragma unroll
        for (int w = 0; w < NW; ++w) s += ired[w];
        last_idx = s - 1;
    }

    // ---- lv = input[b, last_idx, :] ----
    if (tid < Dn) lv[tid] = inb[(size_t)last_idx * Dn + tid];
    __syncthreads();

    // ---- q[h] = sum_d lv[d] * Wt[d,h]  (coalesced across h) ----
    if (tid < Hn) {
        float acc = 0.f;
        #pragma unroll 16
        for (int d = 0; d < Dn; ++d) acc = fmaf(lv[d], Wt[d * Hn + tid], acc);
        qs[tid] = acc;
    }
    __syncthreads();

    // ---- u[d] = sum_h Wx[d,h] * q[h] ----
    if (tid < Dn) {
        float acc = 0.f;
        const float* wxr = Wx + tid * Hn;
        #pragma unroll 16
        for (int h = 0; h < Hn; ++h) acc = fmaf(wxr[h], qs[h], acc);
        us[tid] = acc;
    }
    __syncthreads();

    // ---- phase 1: dot[t] = input[b,t,:] . u ; scores ----
    const float srate = 1.f / (1.f + expf(-rate[0]));
    float dot = 0.f;
    {
        const float4* row = (const float4*)(inb + (size_t)tid * Dn);
        const float4* u4  = (const float4*)us;
        #pragma unroll
        for (int d4 = 0; d4 < Dn / 4; ++d4) {
            float4 xv = row[d4];
            float4 uv = u4[d4];
            dot = fmaf(xv.x, uv.x, dot);
            dot = fmaf(xv.y, uv.y, dot);
            dot = fmaf(xv.z, uv.z, dot);
            dot = fmaf(xv.w, uv.w, dot);
        }
    }
    float sig   = 1.f / (1.f + expf(-dot));
    float decay = (float)(Tn - tid);                       // b_time_decays[t] = T - t
    float denom = srate * (logf(2.72f + (1.f - sig)) * decay);
    float e     = fmaxf(sig / denom, 0.f);                 // relu
    if (mv == 0) e = -1e9f;

    // ---- softmax over T (block reduce max, then sum) ----
    float bmax = e;
    #pragma unroll
    for (int off = 32; off > 0; off >>= 1) bmax = fmaxf(bmax, __shfl_down(bmax, off, 64));
    if (lane == 0) red[wid] = bmax;
    __syncthreads();
    {
        float mx = red[0];
        #pragma unroll
        for (int w = 1; w < NW; ++w) mx = fmaxf(mx, red[w]);
        bmax = mx;
    }
    __syncthreads();   // red reuse
    float p = expf(e - bmax);
    float bsum = p;
    #pragma unroll
    for (int off = 32; off > 0; off >>= 1) bsum += __shfl_down(bsum, off, 64);
    if (lane == 0) red[wid] = bsum;
    __syncthreads();
    {
        float s = 0.f;
        #pragma unroll
        for (int w = 0; w < NW; ++w) s += red[w];
        bsum = s;
    }
    float av = p / bsum;
    sa[tid] = av;
    out_a[(size_t)b * Tn + tid] = av;
    __syncthreads();

    // ---- phase 2: v[d] = sum_t a[t] * input[b,t,d] ----
    // 16 groups x 32 float4-columns; group g handles rows t = k*16 + g
    // -> a full wave (2 groups) reads 1KB contiguous per iteration.
    {
        const int c = tid & 31;          // float4 column 0..31
        const int g = tid >> 5;          // group 0..15
        const float4* in4 = (const float4*)inb;
        float4 acc = make_float4(0.f, 0.f, 0.f, 0.f);
        #pragma unroll 4
        for (int k = 0; k < Tn / 16; ++k) {
            const int tt = k * 16 + g;
            const float a_t = sa[tt];
            float4 xv = in4[(size_t)tt * 32 + c];
            acc.x = fmaf(a_t, xv.x, acc.x);
            acc.y = fmaf(a_t, xv.y, acc.y);
            acc.z = fmaf(a_t, xv.z, acc.z);
            acc.w = fmaf(a_t, xv.w, acc.w);
        }
        vp[g][c] = acc;
    }
    __syncthreads();
    if (tid < 32) {
        float4 s = vp[0][tid];
        #pragma unroll
        for (int g2 = 1; g2 < 16; ++g2) {
            float4 x = vp[g2][tid];
            s.x += x.x; s.y += x.y; s.z += x.z; s.w += x.w;
        }
        ((float4*)(out_v + (size_t)b * Dn))[tid] = s;
    }
}

extern "C" void kernel_launch(void* const* d_in, const int* in_sizes, int n_in,
                              void* d_out, int out_size, void* d_ws, size_t ws_size,
                              hipStream_t stream) {
    const float* input = (const float*)d_in[0];   // [B,T,D]
    const int*   mask  = (const int*)d_in[1];     // [B,T]
    const float* Wt    = (const float*)d_in[2];   // [D,H]
    const float* Wx    = (const float*)d_in[3];   // [D,H]
    const float* rate  = (const float*)d_in[4];   // [1]

    float* out   = (float*)d_out;
    float* out_v = out;                 // [B,D] first (return order: v, a)
    float* out_a = out + Bn * Dn;       // [B,T]

    single_attn_kernel<<<Bn, NT, 0, stream>>>(input, mask, Wt, Wx, rate, out_v, out_a);
}